// Round 1
// baseline (476.403 us; speedup 1.0000x reference)
//
#include <hip/hip_runtime.h>

#define NPATCH 16384
#define NDB    16384
#define WS9    9
#define JCH    8
#define CHUNK  (NDB / JCH)      // 2048
#define BAND_LO 0.8998f         // 0.9 - 2e-4
#define BAND_HI 0.9002f         // 0.9 + 2e-4

// numpy-order norm of 9 elements:
//   np.linalg.norm => sqrt(add.reduce(x*x)) with pairwise-8 + remainder,
//   plain mul/add (no fma contraction).
__device__ __forceinline__ float np_norm9(const float* v) {
#pragma clang fp contract(off)
    float q0 = v[0] * v[0], q1 = v[1] * v[1], q2 = v[2] * v[2], q3 = v[3] * v[3];
    float q4 = v[4] * v[4], q5 = v[5] * v[5], q6 = v[6] * v[6], q7 = v[7] * v[7];
    float q8 = v[8] * v[8];
    float s = ((q0 + q1) + (q2 + q3)) + ((q4 + q5) + (q6 + q7));
    s = s + q8;
    return sqrtf(s);
}

// K0: zero band counter, compute db inverse norms, copy db rows to out[0:m*9].
__global__ __launch_bounds__(256) void k_prep(const float* __restrict__ db,
                                              float* __restrict__ out,
                                              float* __restrict__ invd,
                                              int* __restrict__ band_count) {
    int j = blockIdx.x * 256 + threadIdx.x;
    if (j == 0) *band_count = 0;
    if (j < NDB) {
        float d[WS9];
#pragma unroll
        for (int k = 0; k < WS9; k++) d[k] = db[j * WS9 + k];
        invd[j] = 1.0f / np_norm9(d);
#pragma unroll
        for (int k = 0; k < WS9; k++) out[j * WS9 + k] = d[k];
    }
}

// K1: phase 1. Thread = one patch, block.y = db chunk. db rows are wave-uniform
// -> scalar (s_load) traffic on the SALU/SMEM pipe; VALU does 9 fma + mul + max.
__global__ __launch_bounds__(256) void k_phase1(const float* __restrict__ patches,
                                                const float* __restrict__ db,
                                                const float* __restrict__ invd,
                                                float* __restrict__ partial,
                                                float* __restrict__ normp) {
    int i = blockIdx.x * 256 + threadIdx.x;
    int c = blockIdx.y;
    float p[WS9];
#pragma unroll
    for (int k = 0; k < WS9; k++) p[k] = patches[i * WS9 + k];
    float maxv = -3.0e38f;
    int j0 = c * CHUNK;
#pragma unroll 4
    for (int j = j0; j < j0 + CHUNK; j++) {
        float dot = 0.0f;
#pragma unroll
        for (int k = 0; k < WS9; k++) dot = fmaf(p[k], db[j * WS9 + k], dot);
        maxv = fmaxf(maxv, dot * invd[j]);
    }
    partial[c * NPATCH + i] = maxv;
    if (c == 0) normp[i] = np_norm9(p);
}

// K2: combine chunk maxima; classify. Definite patches write their output row
// here; band patches go to the list for exact re-check.
__global__ __launch_bounds__(256) void k_combine(const float* __restrict__ patches,
                                                 const float* __restrict__ partial,
                                                 const float* __restrict__ normp,
                                                 float* __restrict__ out,
                                                 int* __restrict__ band_list,
                                                 int* __restrict__ band_count) {
    int i = blockIdx.x * 256 + threadIdx.x;
    float maxv = partial[i];
#pragma unroll
    for (int c = 1; c < JCH; c++) maxv = fmaxf(maxv, partial[c * NPATCH + i]);
    float cosmax = maxv * (1.0f / normp[i]);
    if (cosmax >= BAND_LO && cosmax < BAND_HI) {
        int idx = atomicAdd(band_count, 1);
        band_list[idx] = i;
        return;  // row written by phase 2
    }
    int hit = (cosmax >= BAND_HI) ? 1 : 0;
#pragma unroll
    for (int k = 0; k < WS9; k++)
        out[(NDB + i) * WS9 + k] = hit ? 0.0f : patches[i * WS9 + k];
}

// K3: exact numpy-mirror re-check for band patches. One block per list entry
// (grid-stride). Sequential fmaf dot, numpy-order norms, IEEE div, and the
// comparison done in f64 because numpy promotes cos(f32) < 0.9(f64).
__global__ __launch_bounds__(256) void k_phase2(const float* __restrict__ patches,
                                                const float* __restrict__ db,
                                                const int* __restrict__ band_list,
                                                const int* __restrict__ band_count,
                                                float* __restrict__ out) {
    __shared__ float sp[WS9];
    __shared__ float snp;
    __shared__ int shit;
    int nb = *band_count;
    for (int idx = blockIdx.x; idx < nb; idx += gridDim.x) {
        int i = band_list[idx];
        if (threadIdx.x == 0) {
            float p[WS9];
            for (int k = 0; k < WS9; k++) { p[k] = patches[i * WS9 + k]; sp[k] = p[k]; }
            snp = np_norm9(p);
            shit = 0;
        }
        __syncthreads();
        float p[WS9];
#pragma unroll
        for (int k = 0; k < WS9; k++) p[k] = sp[k];
        float npn = snp;
        int hit = 0;
        for (int j = (int)threadIdx.x; j < NDB; j += 256) {
            float d[WS9];
#pragma unroll
            for (int k = 0; k < WS9; k++) d[k] = db[j * WS9 + k];
            float dot = 0.0f;
#pragma unroll
            for (int k = 0; k < WS9; k++) dot = fmaf(p[k], d[k], dot);
            float nd = np_norm9(d);
            float cs = dot / (npn * nd);          // IEEE-rounded fp32 divide
            if (!((double)cs < 0.9)) hit = 1;     // numpy: f32 promoted to f64
        }
        if (hit) atomicOr(&shit, 1);
        __syncthreads();
        int m = shit;
        if (threadIdx.x < WS9)
            out[(NDB + i) * WS9 + threadIdx.x] = m ? 0.0f : sp[threadIdx.x];
        __syncthreads();  // protect sp/snp/shit before next list entry
    }
}

extern "C" void kernel_launch(void* const* d_in, const int* in_sizes, int n_in,
                              void* d_out, int out_size, void* d_ws, size_t ws_size,
                              hipStream_t stream) {
    const float* patches = (const float*)d_in[0];  // [16384][9]
    const float* db      = (const float*)d_in[1];  // [16384][9]
    float* out = (float*)d_out;                    // [32768][9]

    // ws layout (f32 units)
    float* ws_f      = (float*)d_ws;
    float* invd      = ws_f;                        // 16384
    float* normp     = ws_f + NDB;                  // 16384
    float* partial   = ws_f + 2 * NDB;              // JCH*16384 = 131072
    int*   band_list = (int*)(ws_f + 2 * NDB + JCH * NPATCH);      // 16384
    int*   band_count= (int*)(ws_f + 2 * NDB + JCH * NPATCH + NPATCH); // 1
    // total ~720 KB

    k_prep<<<dim3(NDB / 256), dim3(256), 0, stream>>>(db, out, invd, band_count);
    k_phase1<<<dim3(NPATCH / 256, JCH), dim3(256), 0, stream>>>(patches, db, invd,
                                                                partial, normp);
    k_combine<<<dim3(NPATCH / 256), dim3(256), 0, stream>>>(patches, partial, normp,
                                                            out, band_list, band_count);
    k_phase2<<<dim3(512), dim3(256), 0, stream>>>(patches, db, band_list, band_count, out);
}

// Round 2
// 131.445 us; speedup vs baseline: 3.6244x; 3.6244x over previous
//
#include <hip/hip_runtime.h>

#define NPATCH 16384
#define NDB    16384
#define WS9    9
#define JCH    128
#define CHUNK  (NDB / JCH)      // 128 db rows per chunk
#define PPT    8                // patches per thread
#define BAND_LO 0.8998f         // 0.9 - 2e-4
#define BAND_HI 0.9002f         // 0.9 + 2e-4

// numpy-order norm of 9 elements: sqrt(pairwise-8 + remainder), no contraction.
__device__ __forceinline__ float np_norm9(const float* v) {
#pragma clang fp contract(off)
    float q0 = v[0] * v[0], q1 = v[1] * v[1], q2 = v[2] * v[2], q3 = v[3] * v[3];
    float q4 = v[4] * v[4], q5 = v[5] * v[5], q6 = v[6] * v[6], q7 = v[7] * v[7];
    float q8 = v[8] * v[8];
    float s = ((q0 + q1) + (q2 + q3)) + ((q4 + q5) + (q6 + q7));
    s = s + q8;
    return sqrtf(s);
}

// order-preserving float <-> uint encoding for unsigned atomicMax
__device__ __forceinline__ unsigned enc_f(float f) {
    unsigned u = __float_as_uint(f);
    return (u & 0x80000000u) ? ~u : (u | 0x80000000u);
}
__device__ __forceinline__ float dec_f(unsigned k) {
    return __uint_as_float((k & 0x80000000u) ? (k & 0x7fffffffu) : ~k);
}

// K0: init counters/maxenc, db inverse norms, patch norms, copy db rows to out.
__global__ __launch_bounds__(256) void k_prep(const float* __restrict__ patches,
                                              const float* __restrict__ db,
                                              float* __restrict__ out,
                                              float* __restrict__ invd,
                                              float* __restrict__ normp,
                                              unsigned* __restrict__ maxenc,
                                              int* __restrict__ band_count) {
    int j = blockIdx.x * 256 + threadIdx.x;
    if (j == 0) *band_count = 0;
    if (j < NDB) {
        float d[WS9];
#pragma unroll
        for (int k = 0; k < WS9; k++) d[k] = db[j * WS9 + k];
        invd[j] = 1.0f / np_norm9(d);
#pragma unroll
        for (int k = 0; k < WS9; k++) out[j * WS9 + k] = d[k];
        float p[WS9];
#pragma unroll
        for (int k = 0; k < WS9; k++) p[k] = patches[j * WS9 + k];
        normp[j] = np_norm9(p);
        maxenc[j] = 0u;   // encodes -NaN; overwritten by every chunk's atomicMax
    }
}

// K1: phase 1. blockIdx.x = patch group (2048 patches), blockIdx.y = db chunk.
// db chunk staged in LDS (row padded to 12 floats, invd in slot 9). Each thread
// carries 8 patches in VGPRs; per j: 3 broadcast ds_read_b128 + 8*(9 fma+mul+max).
__global__ __launch_bounds__(256, 4) void k_phase1(const float* __restrict__ patches,
                                                   const float* __restrict__ db,
                                                   const float* __restrict__ invd,
                                                   unsigned* __restrict__ maxenc) {
    __shared__ __align__(16) float sdb[CHUNK * 12];
    int jbase = blockIdx.y * CHUNK;
    // cooperative stage: CHUNK*9 = 1152 elements
    for (int e = threadIdx.x; e < CHUNK * WS9; e += 256) {
        int r = e / WS9, c = e - WS9 * r;
        sdb[r * 12 + c] = db[jbase * WS9 + e];
    }
    if (threadIdx.x < CHUNK) sdb[threadIdx.x * 12 + 9] = invd[jbase + threadIdx.x];
    __syncthreads();

    int ibase = blockIdx.x * (256 * PPT) + threadIdx.x;
    float p[PPT][WS9];
#pragma unroll
    for (int pp = 0; pp < PPT; pp++) {
        int i = ibase + 256 * pp;
#pragma unroll
        for (int k = 0; k < WS9; k++) p[pp][k] = patches[i * WS9 + k];
    }
    float mv[PPT];
#pragma unroll
    for (int pp = 0; pp < PPT; pp++) mv[pp] = -3.0e38f;

#pragma unroll 2
    for (int j = 0; j < CHUNK; j++) {
        float4 r0 = *(const float4*)&sdb[j * 12];
        float4 r1 = *(const float4*)&sdb[j * 12 + 4];
        float4 r2 = *(const float4*)&sdb[j * 12 + 8];
        float d0 = r0.x, d1 = r0.y, d2 = r0.z, d3 = r0.w;
        float d4 = r1.x, d5 = r1.y, d6 = r1.z, d7 = r1.w;
        float d8 = r2.x, sinv = r2.y;
#pragma unroll
        for (int pp = 0; pp < PPT; pp++) {
            float dot = 0.0f;
            dot = fmaf(p[pp][0], d0, dot);
            dot = fmaf(p[pp][1], d1, dot);
            dot = fmaf(p[pp][2], d2, dot);
            dot = fmaf(p[pp][3], d3, dot);
            dot = fmaf(p[pp][4], d4, dot);
            dot = fmaf(p[pp][5], d5, dot);
            dot = fmaf(p[pp][6], d6, dot);
            dot = fmaf(p[pp][7], d7, dot);
            dot = fmaf(p[pp][8], d8, dot);
            mv[pp] = fmaxf(mv[pp], dot * sinv);
        }
    }
#pragma unroll
    for (int pp = 0; pp < PPT; pp++)
        atomicMax(&maxenc[ibase + 256 * pp], enc_f(mv[pp]));
}

// K2: classify from global max; definite rows written here, band -> list.
__global__ __launch_bounds__(256) void k_combine(const float* __restrict__ patches,
                                                 const unsigned* __restrict__ maxenc,
                                                 const float* __restrict__ normp,
                                                 float* __restrict__ out,
                                                 int* __restrict__ band_list,
                                                 int* __restrict__ band_count) {
    int i = blockIdx.x * 256 + threadIdx.x;
    float cosmax = dec_f(maxenc[i]) * (1.0f / normp[i]);
    if (cosmax >= BAND_LO && cosmax < BAND_HI) {
        int idx = atomicAdd(band_count, 1);
        band_list[idx] = i;
        return;  // row written by phase 2
    }
    int hit = (cosmax >= BAND_HI) ? 1 : 0;
#pragma unroll
    for (int k = 0; k < WS9; k++)
        out[(NDB + i) * WS9 + k] = hit ? 0.0f : patches[i * WS9 + k];
}

// K3: exact numpy-mirror re-check for band patches (unchanged, proven absmax=0).
__global__ __launch_bounds__(256) void k_phase2(const float* __restrict__ patches,
                                                const float* __restrict__ db,
                                                const int* __restrict__ band_list,
                                                const int* __restrict__ band_count,
                                                float* __restrict__ out) {
    __shared__ float sp[WS9];
    __shared__ float snp;
    __shared__ int shit;
    int nb = *band_count;
    for (int idx = blockIdx.x; idx < nb; idx += gridDim.x) {
        int i = band_list[idx];
        if (threadIdx.x == 0) {
            float p[WS9];
            for (int k = 0; k < WS9; k++) { p[k] = patches[i * WS9 + k]; sp[k] = p[k]; }
            snp = np_norm9(p);
            shit = 0;
        }
        __syncthreads();
        float p[WS9];
#pragma unroll
        for (int k = 0; k < WS9; k++) p[k] = sp[k];
        float npn = snp;
        int hit = 0;
        for (int j = (int)threadIdx.x; j < NDB; j += 256) {
            float d[WS9];
#pragma unroll
            for (int k = 0; k < WS9; k++) d[k] = db[j * WS9 + k];
            float dot = 0.0f;
#pragma unroll
            for (int k = 0; k < WS9; k++) dot = fmaf(p[k], d[k], dot);
            float nd = np_norm9(d);
            float cs = dot / (npn * nd);          // IEEE fp32 divide
            if (!((double)cs < 0.9)) hit = 1;     // numpy promotes to f64
        }
        if (hit) atomicOr(&shit, 1);
        __syncthreads();
        int m = shit;
        if (threadIdx.x < WS9)
            out[(NDB + i) * WS9 + threadIdx.x] = m ? 0.0f : sp[threadIdx.x];
        __syncthreads();
    }
}

extern "C" void kernel_launch(void* const* d_in, const int* in_sizes, int n_in,
                              void* d_out, int out_size, void* d_ws, size_t ws_size,
                              hipStream_t stream) {
    const float* patches = (const float*)d_in[0];  // [16384][9]
    const float* db      = (const float*)d_in[1];  // [16384][9]
    float* out = (float*)d_out;                    // [32768][9]

    // ws layout (f32 units): invd | normp | maxenc | band_list | band_count
    float*    ws_f       = (float*)d_ws;
    float*    invd       = ws_f;                   // 16384
    float*    normp      = ws_f + NDB;             // 16384
    unsigned* maxenc     = (unsigned*)(ws_f + 2 * NDB);          // 16384
    int*      band_list  = (int*)(ws_f + 3 * NDB);               // 16384
    int*      band_count = (int*)(ws_f + 4 * NDB);               // 1
    // total ~256 KB

    k_prep<<<dim3(NDB / 256), dim3(256), 0, stream>>>(patches, db, out, invd,
                                                      normp, maxenc, band_count);
    k_phase1<<<dim3(NPATCH / (256 * PPT), JCH), dim3(256), 0, stream>>>(
        patches, db, invd, maxenc);
    k_combine<<<dim3(NPATCH / 256), dim3(256), 0, stream>>>(patches, maxenc, normp,
                                                            out, band_list, band_count);
    k_phase2<<<dim3(512), dim3(256), 0, stream>>>(patches, db, band_list, band_count, out);
}

// Round 3
// 100.986 us; speedup vs baseline: 4.7175x; 1.3016x over previous
//
#include <hip/hip_runtime.h>

#define NPATCH 16384
#define NDB    16384
#define WS9    9
#define KP     16               // K padded 9 -> 16 for 32x32x16 MFMA
#define JCH    16               // db chunks (grid.y)
#define CHUNK  (NDB / JCH)      // 1024 rows per chunk
#define TILES  (CHUNK / 32)     // 32 j-tiles per chunk
#define BAND_LO 0.8998f         // 0.9 - 2e-4  (split-bf16 err < 1e-5)
#define BAND_HI 0.9002f         // 0.9 + 2e-4

typedef short bf16x8 __attribute__((ext_vector_type(8)));
typedef float f32x16 __attribute__((ext_vector_type(16)));

// numpy-order norm of 9 elements: sqrt(pairwise-8 + remainder), no contraction.
__device__ __forceinline__ float np_norm9(const float* v) {
#pragma clang fp contract(off)
    float q0 = v[0] * v[0], q1 = v[1] * v[1], q2 = v[2] * v[2], q3 = v[3] * v[3];
    float q4 = v[4] * v[4], q5 = v[5] * v[5], q6 = v[6] * v[6], q7 = v[7] * v[7];
    float q8 = v[8] * v[8];
    float s = ((q0 + q1) + (q2 + q3)) + ((q4 + q5) + (q6 + q7));
    s = s + q8;
    return sqrtf(s);
}

// order-preserving float <-> uint for unsigned atomicMax
__device__ __forceinline__ unsigned enc_f(float f) {
    unsigned u = __float_as_uint(f);
    return (u & 0x80000000u) ? ~u : (u | 0x80000000u);
}
__device__ __forceinline__ float dec_f(unsigned k) {
    return __uint_as_float((k & 0x80000000u) ? (k & 0x7fffffffu) : ~k);
}

// fp32 -> bf16 RTNE (no NaN inputs here), and back
__device__ __forceinline__ unsigned short f2bf(float x) {
    unsigned u = __float_as_uint(x);
    return (unsigned short)((u + 0x7fffu + ((u >> 16) & 1u)) >> 16);
}
__device__ __forceinline__ float bf2f(unsigned short h) {
    return __uint_as_float(((unsigned)h) << 16);
}

// K0: init maxenc/band_count; build prescaled split-bf16 operands:
//   dn = db[j]/|db[j]|  -> dn_hi + dn_lo   (K-padded to 16, zeros)
//   pn = patch[i]/|p[i]| -> pn_hi + pn_lo
__global__ __launch_bounds__(256) void k_prep(const float* __restrict__ patches,
                                              const float* __restrict__ db,
                                              unsigned short* __restrict__ pn_hi,
                                              unsigned short* __restrict__ pn_lo,
                                              unsigned short* __restrict__ dn_hi,
                                              unsigned short* __restrict__ dn_lo,
                                              unsigned* __restrict__ maxenc,
                                              int* __restrict__ band_count) {
    int j = blockIdx.x * 256 + threadIdx.x;
    if (j == 0) *band_count = 0;
    maxenc[j] = 0u;   // below enc of any finite value

    float d[WS9];
#pragma unroll
    for (int k = 0; k < WS9; k++) d[k] = db[j * WS9 + k];
    float invd = 1.0f / np_norm9(d);
#pragma unroll
    for (int k = 0; k < KP; k++) {
        float v = (k < WS9) ? d[k] * invd : 0.0f;
        unsigned short h = f2bf(v);
        dn_hi[j * KP + k] = h;
        dn_lo[j * KP + k] = f2bf(v - bf2f(h));
    }

    float p[WS9];
#pragma unroll
    for (int k = 0; k < WS9; k++) p[k] = patches[j * WS9 + k];
    float invp = 1.0f / np_norm9(p);
#pragma unroll
    for (int k = 0; k < KP; k++) {
        float v = (k < WS9) ? p[k] * invp : 0.0f;
        unsigned short h = f2bf(v);
        pn_hi[j * KP + k] = h;
        pn_lo[j * KP + k] = f2bf(v - bf2f(h));
    }
}

// K1: phase 1 via split-bf16 MFMA. A = db-side (rows=j), B = patch-side
// (cols=i). Each wave: 2 i-subtiles (64 patches) register-resident, loops
// 32 j-tiles of its chunk; dot = hi*hi + hi*lo + lo*hi chained into one
// accumulator from a pinned zero-C. Max over j is reg-max + half-shuffle —
// robust to any j/row permutation in the A fragment mapping.
__global__ __launch_bounds__(256) void k_phase1(const unsigned short* __restrict__ pn_hi,
                                                const unsigned short* __restrict__ pn_lo,
                                                const unsigned short* __restrict__ dn_hi,
                                                const unsigned short* __restrict__ dn_lo,
                                                unsigned* __restrict__ maxenc) {
    int lane = threadIdx.x & 63;
    int wave = threadIdx.x >> 6;
    int col = lane & 31;
    int half = lane >> 5;
    int i0 = blockIdx.x * 256 + wave * 64;

    const bf16x8* Bh = (const bf16x8*)pn_hi;   // 2 frags per row of 16
    const bf16x8* Bl = (const bf16x8*)pn_lo;
    bf16x8 b_hi0 = Bh[(i0 + col) * 2 + half];
    bf16x8 b_lo0 = Bl[(i0 + col) * 2 + half];
    bf16x8 b_hi1 = Bh[(i0 + 32 + col) * 2 + half];
    bf16x8 b_lo1 = Bl[(i0 + 32 + col) * 2 + half];

    int jrow = blockIdx.y * CHUNK + col;
    const bf16x8* Ah = (const bf16x8*)dn_hi + (size_t)jrow * 2 + half;
    const bf16x8* Al = (const bf16x8*)dn_lo + (size_t)jrow * 2 + half;

    f32x16 zc = {0.f,0.f,0.f,0.f,0.f,0.f,0.f,0.f,0.f,0.f,0.f,0.f,0.f,0.f,0.f,0.f};
    float rm0 = -3.0e38f, rm1 = -3.0e38f;

    bf16x8 a_h = Ah[0], a_l = Al[0];
#pragma unroll 2
    for (int t = 0; t < TILES; ++t) {
        bf16x8 a_h_n = a_h, a_l_n = a_l;
        if (t + 1 < TILES) {            // prefetch next tile (32 rows = 64 frags)
            a_h_n = Ah[(t + 1) * 64];
            a_l_n = Al[(t + 1) * 64];
        }
        f32x16 acc0 = __builtin_amdgcn_mfma_f32_32x32x16_bf16(a_h, b_hi0, zc, 0, 0, 0);
        acc0 = __builtin_amdgcn_mfma_f32_32x32x16_bf16(a_h, b_lo0, acc0, 0, 0, 0);
        acc0 = __builtin_amdgcn_mfma_f32_32x32x16_bf16(a_l, b_hi0, acc0, 0, 0, 0);
        f32x16 acc1 = __builtin_amdgcn_mfma_f32_32x32x16_bf16(a_h, b_hi1, zc, 0, 0, 0);
        acc1 = __builtin_amdgcn_mfma_f32_32x32x16_bf16(a_h, b_lo1, acc1, 0, 0, 0);
        acc1 = __builtin_amdgcn_mfma_f32_32x32x16_bf16(a_l, b_hi1, acc1, 0, 0, 0);
#pragma unroll
        for (int r = 0; r < 16; ++r) {
            rm0 = fmaxf(rm0, acc0[r]);
            rm1 = fmaxf(rm1, acc1[r]);
        }
        a_h = a_h_n;
        a_l = a_l_n;
    }
    // combine the two lane-halves (each covers 16 of the 32 j-rows per tile)
    rm0 = fmaxf(rm0, __shfl_xor(rm0, 32, 64));
    rm1 = fmaxf(rm1, __shfl_xor(rm1, 32, 64));
    unsigned e = half ? enc_f(rm1) : enc_f(rm0);
    int ti = half ? (i0 + 32 + col) : (i0 + col);
    atomicMax(&maxenc[ti], e);
}

// K2: classify from global cos-max (already normalized); copy db rows to out;
// definite patch rows written here, band patches -> list for exact recheck.
__global__ __launch_bounds__(256) void k_combine(const float* __restrict__ patches,
                                                 const float* __restrict__ db,
                                                 const unsigned* __restrict__ maxenc,
                                                 float* __restrict__ out,
                                                 int* __restrict__ band_list,
                                                 int* __restrict__ band_count) {
    int i = blockIdx.x * 256 + threadIdx.x;
#pragma unroll
    for (int k = 0; k < WS9; k++) out[i * WS9 + k] = db[i * WS9 + k];
    float cosmax = dec_f(maxenc[i]);
    if (cosmax >= BAND_LO && cosmax < BAND_HI) {
        int idx = atomicAdd(band_count, 1);
        band_list[idx] = i;
        return;  // row written by phase 2
    }
    int hit = (cosmax >= BAND_HI) ? 1 : 0;
#pragma unroll
    for (int k = 0; k < WS9; k++)
        out[(NDB + i) * WS9 + k] = hit ? 0.0f : patches[i * WS9 + k];
}

// K3: exact numpy-mirror recheck for band patches (proven absmax=0).
__global__ __launch_bounds__(256) void k_phase2(const float* __restrict__ patches,
                                                const float* __restrict__ db,
                                                const int* __restrict__ band_list,
                                                const int* __restrict__ band_count,
                                                float* __restrict__ out) {
    __shared__ float sp[WS9];
    __shared__ float snp;
    __shared__ int shit;
    int nb = *band_count;
    for (int idx = blockIdx.x; idx < nb; idx += gridDim.x) {
        int i = band_list[idx];
        if (threadIdx.x == 0) {
            float p[WS9];
            for (int k = 0; k < WS9; k++) { p[k] = patches[i * WS9 + k]; sp[k] = p[k]; }
            snp = np_norm9(p);
            shit = 0;
        }
        __syncthreads();
        float p[WS9];
#pragma unroll
        for (int k = 0; k < WS9; k++) p[k] = sp[k];
        float npn = snp;
        int hit = 0;
        for (int j = (int)threadIdx.x; j < NDB; j += 256) {
            float d[WS9];
#pragma unroll
            for (int k = 0; k < WS9; k++) d[k] = db[j * WS9 + k];
            float dot = 0.0f;
#pragma unroll
            for (int k = 0; k < WS9; k++) dot = fmaf(p[k], d[k], dot);
            float nd = np_norm9(d);
            float cs = dot / (npn * nd);          // IEEE fp32 divide
            if (!((double)cs < 0.9)) hit = 1;     // numpy promotes to f64
        }
        if (hit) atomicOr(&shit, 1);
        __syncthreads();
        int m = shit;
        if (threadIdx.x < WS9)
            out[(NDB + i) * WS9 + threadIdx.x] = m ? 0.0f : sp[threadIdx.x];
        __syncthreads();
    }
}

extern "C" void kernel_launch(void* const* d_in, const int* in_sizes, int n_in,
                              void* d_out, int out_size, void* d_ws, size_t ws_size,
                              hipStream_t stream) {
    const float* patches = (const float*)d_in[0];  // [16384][9]
    const float* db      = (const float*)d_in[1];  // [16384][9]
    float* out = (float*)d_out;                    // [32768][9]

    // ws layout (bytes):
    //   maxenc     @ 0        (16384 u32 = 64 KB)
    //   band_list  @ 64 KB    (16384 i32 = 64 KB)
    //   band_count @ 128 KB   (16 B slot)
    //   pn_hi/pn_lo/dn_hi/dn_lo @ 128 KB + 16, each 16384*16*2 B = 512 KB
    char* wsb = (char*)d_ws;
    unsigned*       maxenc     = (unsigned*)wsb;
    int*            band_list  = (int*)(wsb + (size_t)64 * 1024);
    int*            band_count = (int*)(wsb + (size_t)128 * 1024);
    unsigned short* pn_hi      = (unsigned short*)(wsb + (size_t)128 * 1024 + 16);
    unsigned short* pn_lo      = pn_hi + (size_t)NPATCH * KP;
    unsigned short* dn_hi      = pn_lo + (size_t)NPATCH * KP;
    unsigned short* dn_lo      = dn_hi + (size_t)NDB * KP;
    // total ~2.25 MB

    k_prep<<<dim3(NDB / 256), dim3(256), 0, stream>>>(patches, db, pn_hi, pn_lo,
                                                      dn_hi, dn_lo, maxenc, band_count);
    k_phase1<<<dim3(NPATCH / 256, JCH), dim3(256), 0, stream>>>(pn_hi, pn_lo,
                                                                dn_hi, dn_lo, maxenc);
    k_combine<<<dim3(NPATCH / 256), dim3(256), 0, stream>>>(patches, db, maxenc,
                                                            out, band_list, band_count);
    k_phase2<<<dim3(512), dim3(256), 0, stream>>>(patches, db, band_list, band_count, out);
}

// Round 5
// 98.320 us; speedup vs baseline: 4.8454x; 1.0271x over previous
//
#include <hip/hip_runtime.h>

#define NPATCH 16384
#define NDB    16384
#define WS9    9
#define KP     16               // K padded 9 -> 16 for 32x32x16 MFMA
#define JCH    32               // db chunks (grid.y)
#define CHUNK  (NDB / JCH)      // 512 rows per chunk
#define TILES  (CHUNK / 32)     // 16 j-tiles per chunk
#define BAND_LO 0.8998f         // 0.9 - 2e-4  (split-bf16 err < 1e-5)
#define BAND_HI 0.9002f         // 0.9 + 2e-4
#define COPY_BLOCKS 144         // NDB*9/4/256 float4-copy blocks

typedef short bf16x8 __attribute__((ext_vector_type(8)));
typedef float f32x16 __attribute__((ext_vector_type(16)));

// numpy-order norm of 9 elements: sqrt(pairwise-8 + remainder), no contraction.
__device__ __forceinline__ float np_norm9(const float* v) {
#pragma clang fp contract(off)
    float q0 = v[0] * v[0], q1 = v[1] * v[1], q2 = v[2] * v[2], q3 = v[3] * v[3];
    float q4 = v[4] * v[4], q5 = v[5] * v[5], q6 = v[6] * v[6], q7 = v[7] * v[7];
    float q8 = v[8] * v[8];
    float s = ((q0 + q1) + (q2 + q3)) + ((q4 + q5) + (q6 + q7));
    s = s + q8;
    return sqrtf(s);
}

// fp32 -> bf16 RTNE (no NaN inputs here), and back
__device__ __forceinline__ unsigned short f2bf(float x) {
    unsigned u = __float_as_uint(x);
    return (unsigned short)((u + 0x7fffu + ((u >> 16) & 1u)) >> 16);
}
__device__ __forceinline__ float bf2f(unsigned short h) {
    return __uint_as_float(((unsigned)h) << 16);
}

// load row of 9, normalize, split to bf16 hi/lo, K-pad to 16, pack to LDS as
// 2x int4 per array. (R4 bug: wrote 8 ints through &int4 — UB garbage in
// elements 8..15. Now packs via proper arrays.)
__device__ __forceinline__ void stage_row(const float* __restrict__ src,
                                          unsigned short* dh, unsigned short* dl) {
    float v[WS9];
#pragma unroll
    for (int k = 0; k < WS9; k++) v[k] = src[k];
    float inv = 1.0f / np_norm9(v);
    unsigned short h[KP], l[KP];
#pragma unroll
    for (int k = 0; k < KP; k++) {
        float x = (k < WS9) ? v[k] * inv : 0.0f;
        h[k] = f2bf(x);
        l[k] = f2bf(x - bf2f(h[k]));
    }
    int hw[8], lw[8];
#pragma unroll
    for (int k = 0; k < 8; k++) {
        hw[k] = (int)h[2 * k] | ((int)h[2 * k + 1] << 16);
        lw[k] = (int)l[2 * k] | ((int)l[2 * k + 1] << 16);
    }
    ((int4*)dh)[0] = make_int4(hw[0], hw[1], hw[2], hw[3]);
    ((int4*)dh)[1] = make_int4(hw[4], hw[5], hw[6], hw[7]);
    ((int4*)dl)[0] = make_int4(lw[0], lw[1], lw[2], lw[3]);
    ((int4*)dl)[1] = make_int4(lw[4], lw[5], lw[6], lw[7]);
}

// K1: fused prep + phase1. Block = 256 patches (x) paired with a 512-row db
// chunk (y). Splits computed in-block into LDS; MFMA loop (32x32x16 bf16,
// dot = hi*hi + hi*lo + lo*hi) with A-frags from LDS; chunk cos-max stored
// plain to partial[y][i] (no atomics, no init needed).
__global__ __launch_bounds__(256) void k_phase1(const float* __restrict__ patches,
                                                const float* __restrict__ db,
                                                float* __restrict__ partial,
                                                int* __restrict__ band_count) {
    __shared__ __align__(16) unsigned short s_dnh[CHUNK * KP];
    __shared__ __align__(16) unsigned short s_dnl[CHUNK * KP];
    __shared__ __align__(16) unsigned short s_pnh[256 * KP];
    __shared__ __align__(16) unsigned short s_pnl[256 * KP];

    if (blockIdx.x == 0 && blockIdx.y == 0 && threadIdx.x == 0) *band_count = 0;

    int jbase = blockIdx.y * CHUNK;
    int ibase = blockIdx.x * 256;
#pragma unroll
    for (int rr = 0; rr < CHUNK / 256; rr++) {
        int r = rr * 256 + threadIdx.x;
        stage_row(db + (size_t)(jbase + r) * WS9, &s_dnh[r * KP], &s_dnl[r * KP]);
    }
    stage_row(patches + (size_t)(ibase + threadIdx.x) * WS9,
              &s_pnh[threadIdx.x * KP], &s_pnl[threadIdx.x * KP]);
    __syncthreads();

    int lane = threadIdx.x & 63;
    int wave = threadIdx.x >> 6;
    int col = lane & 31;
    int half = lane >> 5;
    int i0 = ibase + wave * 64;

    const bf16x8* Ph = (const bf16x8*)s_pnh;   // 2 frags per 16-elem row
    const bf16x8* Pl = (const bf16x8*)s_pnl;
    bf16x8 b_hi0 = Ph[(wave * 64 + col) * 2 + half];
    bf16x8 b_lo0 = Pl[(wave * 64 + col) * 2 + half];
    bf16x8 b_hi1 = Ph[(wave * 64 + 32 + col) * 2 + half];
    bf16x8 b_lo1 = Pl[(wave * 64 + 32 + col) * 2 + half];

    const bf16x8* Ah = (const bf16x8*)s_dnh;
    const bf16x8* Al = (const bf16x8*)s_dnl;

    f32x16 zc = {0.f,0.f,0.f,0.f,0.f,0.f,0.f,0.f,0.f,0.f,0.f,0.f,0.f,0.f,0.f,0.f};
    float rm0 = -3.0e38f, rm1 = -3.0e38f;

#pragma unroll 2
    for (int t = 0; t < TILES; ++t) {
        bf16x8 a_h = Ah[(t * 32 + col) * 2 + half];
        bf16x8 a_l = Al[(t * 32 + col) * 2 + half];
        f32x16 acc0 = __builtin_amdgcn_mfma_f32_32x32x16_bf16(a_h, b_hi0, zc, 0, 0, 0);
        acc0 = __builtin_amdgcn_mfma_f32_32x32x16_bf16(a_h, b_lo0, acc0, 0, 0, 0);
        acc0 = __builtin_amdgcn_mfma_f32_32x32x16_bf16(a_l, b_hi0, acc0, 0, 0, 0);
        f32x16 acc1 = __builtin_amdgcn_mfma_f32_32x32x16_bf16(a_h, b_hi1, zc, 0, 0, 0);
        acc1 = __builtin_amdgcn_mfma_f32_32x32x16_bf16(a_h, b_lo1, acc1, 0, 0, 0);
        acc1 = __builtin_amdgcn_mfma_f32_32x32x16_bf16(a_l, b_hi1, acc1, 0, 0, 0);
#pragma unroll
        for (int r = 0; r < 16; ++r) {
            rm0 = fmaxf(rm0, acc0[r]);
            rm1 = fmaxf(rm1, acc1[r]);
        }
    }
    // each lane-half covers 16 of 32 j-rows; combine, then plain store
    rm0 = fmaxf(rm0, __shfl_xor(rm0, 32, 64));
    rm1 = fmaxf(rm1, __shfl_xor(rm1, 32, 64));
    int ti = half ? (i0 + 32 + col) : (i0 + col);
    partial[(size_t)blockIdx.y * NPATCH + ti] = half ? rm1 : rm0;
}

// K2: blocks [0,144) copy db rows to out (float4); blocks [144,208) classify:
// max over 32 chunk-partials, definite rows written, band -> list.
__global__ __launch_bounds__(256) void k_finish(const float* __restrict__ patches,
                                                const float* __restrict__ db,
                                                const float* __restrict__ partial,
                                                float* __restrict__ out,
                                                int* __restrict__ band_list,
                                                int* __restrict__ band_count) {
    int b = blockIdx.x;
    if (b < COPY_BLOCKS) {
        int e = b * 256 + threadIdx.x;          // 36864 float4 = 147456 floats
        ((float4*)out)[e] = ((const float4*)db)[e];
        return;
    }
    int i = (b - COPY_BLOCKS) * 256 + threadIdx.x;
    float cosmax = partial[i];
#pragma unroll
    for (int c = 1; c < JCH; c++) cosmax = fmaxf(cosmax, partial[(size_t)c * NPATCH + i]);
    if (cosmax >= BAND_LO && cosmax < BAND_HI) {
        int idx = atomicAdd(band_count, 1);
        band_list[idx] = i;
        return;  // row written by phase 2
    }
    int hit = (cosmax >= BAND_HI) ? 1 : 0;
#pragma unroll
    for (int k = 0; k < WS9; k++)
        out[(size_t)(NDB + i) * WS9 + k] = hit ? 0.0f : patches[i * WS9 + k];
}

// K3: exact numpy-mirror recheck for band patches (proven absmax=0).
__global__ __launch_bounds__(256) void k_phase2(const float* __restrict__ patches,
                                                const float* __restrict__ db,
                                                const int* __restrict__ band_list,
                                                const int* __restrict__ band_count,
                                                float* __restrict__ out) {
    __shared__ float sp[WS9];
    __shared__ float snp;
    __shared__ int shit;
    int nb = *band_count;
    for (int idx = blockIdx.x; idx < nb; idx += gridDim.x) {
        int i = band_list[idx];
        if (threadIdx.x == 0) {
            float p[WS9];
            for (int k = 0; k < WS9; k++) { p[k] = patches[i * WS9 + k]; sp[k] = p[k]; }
            snp = np_norm9(p);
            shit = 0;
        }
        __syncthreads();
        float p[WS9];
#pragma unroll
        for (int k = 0; k < WS9; k++) p[k] = sp[k];
        float npn = snp;
        int hit = 0;
        for (int j = (int)threadIdx.x; j < NDB; j += 256) {
            float d[WS9];
#pragma unroll
            for (int k = 0; k < WS9; k++) d[k] = db[j * WS9 + k];
            float dot = 0.0f;
#pragma unroll
            for (int k = 0; k < WS9; k++) dot = fmaf(p[k], d[k], dot);
            float nd = np_norm9(d);
            float cs = dot / (npn * nd);          // IEEE fp32 divide
            if (!((double)cs < 0.9)) hit = 1;     // numpy promotes to f64
        }
        if (hit) atomicOr(&shit, 1);
        __syncthreads();
        int m = shit;
        if (threadIdx.x < WS9)
            out[(size_t)(NDB + i) * WS9 + threadIdx.x] = m ? 0.0f : sp[threadIdx.x];
        __syncthreads();
    }
}

extern "C" void kernel_launch(void* const* d_in, const int* in_sizes, int n_in,
                              void* d_out, int out_size, void* d_ws, size_t ws_size,
                              hipStream_t stream) {
    const float* patches = (const float*)d_in[0];  // [16384][9]
    const float* db      = (const float*)d_in[1];  // [16384][9]
    float* out = (float*)d_out;                    // [32768][9]

    // ws layout: partial (JCH*NPATCH f32 = 2 MB) | band_list (64 KB) | band_count
    char* wsb = (char*)d_ws;
    float* partial    = (float*)wsb;
    int*   band_list  = (int*)(wsb + (size_t)JCH * NPATCH * 4);
    int*   band_count = (int*)(wsb + (size_t)JCH * NPATCH * 4 + (size_t)NPATCH * 4);

    k_phase1<<<dim3(NPATCH / 256, JCH), dim3(256), 0, stream>>>(patches, db,
                                                                partial, band_count);
    k_finish<<<dim3(COPY_BLOCKS + NPATCH / 256), dim3(256), 0, stream>>>(
        patches, db, partial, out, band_list, band_count);
    k_phase2<<<dim3(256), dim3(256), 0, stream>>>(patches, db, band_list, band_count, out);
}